// Round 1
// baseline (495.429 us; speedup 1.0000x reference)
//
#include <hip/hip_runtime.h>

typedef unsigned short u16;
typedef unsigned int u32;

typedef __attribute__((ext_vector_type(8))) short bf16x8;
typedef __attribute__((ext_vector_type(4))) float f32x4;

#define LOG2E 1.4426950408889634f
#define SC 0.125f

__device__ __forceinline__ u16 f2bf(float x) {
    union { float f; u32 u; } v; v.f = x;
    u32 r = (v.u + 0x7FFFu + ((v.u >> 16) & 1u)) >> 16;
    return (u16)r;
}
__device__ __forceinline__ float bf2f(u16 x) {
    union { u32 u; float f; } v; v.u = ((u32)x) << 16;
    return v.f;
}

__device__ __forceinline__ void cp16(const u16* g, u16* l) {
    __builtin_amdgcn_global_load_lds(
        (__attribute__((address_space(1))) void*)(g),
        (__attribute__((address_space(3))) void*)(l), 16, 0, 0);
}

// ---------------- hidden fp32 -> bf16 ----------------
__global__ void k_cvt_bf16(const float* __restrict__ src, u16* __restrict__ dst) {
    int i = (blockIdx.x * 256 + threadIdx.x) * 8;
    float4 a = *(const float4*)(src + i);
    float4 b = *(const float4*)(src + i + 4);
    ushort4 o0; o0.x = f2bf(a.x); o0.y = f2bf(a.y); o0.z = f2bf(a.z); o0.w = f2bf(a.w);
    ushort4 o1; o1.x = f2bf(b.x); o1.y = f2bf(b.y); o1.z = f2bf(b.z); o1.w = f2bf(b.w);
    *(ushort4*)(dst + i) = o0;
    *(ushort4*)(dst + i + 4) = o1;
}

// ---------------- W [K][N] fp32 -> Wt [N][K] bf16 ----------------
__global__ void k_wtrans(const float* __restrict__ W, u16* __restrict__ Wt, int K, int N) {
    __shared__ u16 t[64][72];
    int bx = blockIdx.x;            // n block
    int by = blockIdx.y;            // k block
    int r  = threadIdx.x >> 2;      // 0..63
    int cs = threadIdx.x & 3;       // 0..3
    const float* src = W + (by*64 + r)*N + bx*64 + cs*16;
#pragma unroll
    for (int j = 0; j < 16; j += 4) {
        float4 v = *(const float4*)(src + j);
        t[r][cs*16 + j + 0] = f2bf(v.x);
        t[r][cs*16 + j + 1] = f2bf(v.y);
        t[r][cs*16 + j + 2] = f2bf(v.z);
        t[r][cs*16 + j + 3] = f2bf(v.w);
    }
    __syncthreads();
    u16* dst = Wt + (bx*64 + r)*K + by*64 + cs*16;
#pragma unroll
    for (int j = 0; j < 16; ++j) dst[j] = t[cs*16 + j][r];
}

// ---------------- GEMM: C = A[8192][1024] * Bt^T, Bt is [N][1024] bf16 ----------------
// mode 0: outF fp32 [8192][1024] (final projection), grid (64, 8), Bq = WoT
// mode 1: fused QKV scatter to [b][head][s][64] bf16, grid (64, 12)
__global__ __launch_bounds__(256) void k_gemm(
    const u16* __restrict__ A,
    const u16* __restrict__ Bq, const u16* __restrict__ Bk, const u16* __restrict__ Bv,
    float* __restrict__ outF,
    u16* __restrict__ outQ, u16* __restrict__ outK, u16* __restrict__ outV,
    int mode)
{
    __shared__ __align__(16) u16 At[128*32];
    __shared__ __align__(16) u16 Bt[128*32];
    int tid = threadIdx.x;
    int lane = tid & 63, wv = tid >> 6;
    int l15 = lane & 15, quad = lane >> 4;
    int wm = wv >> 1, wn = wv & 1;
    int mb = blockIdx.x, nb = blockIdx.y;

    const u16* Bsrc; int target; int colLocal0;
    if (mode == 0)      { Bsrc = Bq + nb*128*1024;      target = 3; colLocal0 = nb*128; }
    else if (nb < 8)    { Bsrc = Bq + nb*128*1024;      target = 0; colLocal0 = nb*128; }
    else if (nb < 10)   { Bsrc = Bk + (nb-8)*128*1024;  target = 1; colLocal0 = (nb-8)*128; }
    else                { Bsrc = Bv + (nb-10)*128*1024; target = 2; colLocal0 = (nb-10)*128; }
    const u16* Asrc = A + mb*128*1024;

    f32x4 zf = {0.f, 0.f, 0.f, 0.f};
    f32x4 acc[4][4];
#pragma unroll
    for (int i = 0; i < 4; ++i)
#pragma unroll
        for (int j = 0; j < 4; ++j) acc[i][j] = zf;

    for (int kt = 0; kt < 32; ++kt) {
#pragma unroll
        for (int i = 0; i < 2; ++i) {
            int q = i*256 + tid;
            int r = q >> 2, sidx = q & 3;
            int s = sidx ^ ((r >> 1) & 3);           // XOR swizzle of 16B segs
            cp16(Asrc + r*1024 + kt*32 + s*8, At + (i*256 + wv*64)*8);
            cp16(Bsrc + r*1024 + kt*32 + s*8, Bt + (i*256 + wv*64)*8);
        }
        __syncthreads();
        bf16x8 af[4], bfr[4];
#pragma unroll
        for (int mt = 0; mt < 4; ++mt) {
            int row = wm*64 + mt*16 + l15;
            int sidx = quad ^ ((row >> 1) & 3);
            af[mt] = *(const bf16x8*)(At + row*32 + sidx*8);
        }
#pragma unroll
        for (int nt = 0; nt < 4; ++nt) {
            int row = wn*64 + nt*16 + l15;
            int sidx = quad ^ ((row >> 1) & 3);
            bfr[nt] = *(const bf16x8*)(Bt + row*32 + sidx*8);
        }
#pragma unroll
        for (int mt = 0; mt < 4; ++mt)
#pragma unroll
            for (int nt = 0; nt < 4; ++nt)
                acc[mt][nt] = __builtin_amdgcn_mfma_f32_16x16x32_bf16(af[mt], bfr[nt], acc[mt][nt], 0, 0, 0);
        __syncthreads();
    }

#pragma unroll
    for (int mt = 0; mt < 4; ++mt) {
#pragma unroll
        for (int nt = 0; nt < 4; ++nt) {
#pragma unroll
            for (int rr = 0; rr < 4; ++rr) {
                int row = mb*128 + wm*64 + mt*16 + quad*4 + rr;
                int cl  = colLocal0 + wn*64 + nt*16 + l15;
                float v = acc[mt][nt][rr];
                if (target == 3) {
                    outF[row*1024 + cl] = v;
                } else {
                    int b = row >> 11, s = row & 2047;
                    int hh = cl >> 6, d = cl & 63;
                    u16 bv = f2bf(v);
                    if (target == 0)      outQ[((b*16 + hh)*2048 + s)*64 + d] = bv;
                    else if (target == 1) outK[((b*4  + hh)*2048 + s)*64 + d] = bv;
                    else                  outV[((b*4  + hh)*2048 + s)*64 + d] = bv;
                }
            }
        }
    }
}

// ---------------- RMSNorm + RoPE in place on Q (131072 rows) and K (32768 rows) ----------------
__global__ void k_normrope(u16* __restrict__ Q, u16* __restrict__ K,
                           const float* __restrict__ qw, const float* __restrict__ kw,
                           const float* __restrict__ cosp, const float* __restrict__ sinp)
{
    int row = blockIdx.x * 8 + (threadIdx.x >> 5);
    int t = threadIdx.x & 31;
    u16* base; const float* w; int s;
    if (row < 131072) { base = Q + row*64; s = row & 2047; w = qw; }
    else { int r2 = row - 131072; base = K + r2*64; s = r2 & 2047; w = kw; }
    u32 packed = *(const u32*)(base + 2*t);
    float x0 = bf2f((u16)(packed & 0xffffu));
    float x1 = bf2f((u16)(packed >> 16));
    float ss = x0*x0 + x1*x1;
#pragma unroll
    for (int m = 1; m < 32; m <<= 1) ss += __shfl_xor(ss, m, 32);
    float inv = rsqrtf(ss * (1.0f/64.0f) + 1e-6f);
    float w0 = w[2*t], w1 = w[2*t+1];
    float c = cosp[s*64 + 2*t], sn = sinp[s*64 + 2*t];
    float xn0 = x0 * inv * w0, xn1 = x1 * inv * w1;
    float y0 = xn0*c - xn1*sn;
    float y1 = xn1*c + xn0*sn;
    u32 o = (u32)f2bf(y0) | ((u32)f2bf(y1) << 16);
    *(u32*)(base + 2*t) = o;
}

// ---------------- V [bh][s][64] -> VT [bh][64][s] ----------------
__global__ void k_vtrans(const u16* __restrict__ V, u16* __restrict__ VT) {
    __shared__ u16 t[64][72];
    int sb = blockIdx.x;   // 0..31
    int bh = blockIdx.y;   // 0..15
    int r = threadIdx.x >> 2, cs = threadIdx.x & 3;
    const u16* src = V + (bh*2048 + sb*64 + r)*64 + cs*16;
    uint4 v0 = *(const uint4*)(src);
    uint4 v1 = *(const uint4*)(src + 8);
    *(uint4*)&t[r][cs*16]     = v0;
    *(uint4*)&t[r][cs*16 + 8] = v1;
    __syncthreads();
    u16* dst = VT + (bh*64 + r)*2048 + sb*64 + cs*16;
#pragma unroll
    for (int j = 0; j < 16; ++j) dst[j] = t[cs*16 + j][r];
}

// ---------------- flash attention ----------------
// Q [4][16][2048][64], K [4][4][2048][64], VT [4][4][64][2048] -> attn [8192][1024] (bf16)
__global__ __launch_bounds__(256) void k_attn(
    const u16* __restrict__ Q, const u16* __restrict__ K,
    const u16* __restrict__ VT, u16* __restrict__ attn)
{
    __shared__ __align__(16) u16 smem[128*72 + 64*64 + 64*64];
    u16* smemP = smem;              // [128][72] P; first [128][64] doubles as Q stage
    u16* smemK = smem + 128*72;     // [64][64] swizzled
    u16* smemV = smemK + 64*64;     // [64][64] swizzled (VT tile)

    int tid = threadIdx.x;
    int lane = tid & 63, wv = tid >> 6;
    int l15 = lane & 15, quad = lane >> 4;
    int qt = blockIdx.x, h = blockIdx.y, b = blockIdx.z;
    int q0 = qt * 128;
    const u16* Qg = Q + ((b*16 + h)*2048 + q0)*64;
    const u16* Kg = K + ((b*4 + (h >> 2))*2048)*64;
    const u16* Vg = VT + (b*4 + (h >> 2))*64*2048;

    // stage Q tile [128][64]
#pragma unroll
    for (int i = 0; i < 4; ++i) {
        int q = i*256 + tid;
        int r = q >> 3, s = q & 7;
        cp16(Qg + r*64 + s*8, smemP + (i*256 + wv*64)*8);
    }
    __syncthreads();
    bf16x8 qf[2][2];
#pragma unroll
    for (int mt = 0; mt < 2; ++mt)
#pragma unroll
        for (int ks = 0; ks < 2; ++ks)
            qf[mt][ks] = *(const bf16x8*)(smemP + (wv*32 + mt*16 + l15)*64 + ks*32 + quad*8);
    __syncthreads();   // P region may now overwrite Q stage

    f32x4 zf = {0.f, 0.f, 0.f, 0.f};
    float m_i[2][4], l_i[2][4];
    f32x4 o[2][4];
#pragma unroll
    for (int mt = 0; mt < 2; ++mt) {
#pragma unroll
        for (int r = 0; r < 4; ++r) { m_i[mt][r] = -1e30f; l_i[mt][r] = 0.f; }
#pragma unroll
        for (int d = 0; d < 4; ++d) o[mt][d] = zf;
    }

    int ktmax = (q0 + 127) >> 6;
    for (int kt = 0; kt <= ktmax; ++kt) {
#pragma unroll
        for (int i = 0; i < 2; ++i) {
            int q = i*256 + tid;
            int r = q >> 3, sidx = q & 7;
            int s = sidx ^ (r & 7);
            cp16(Kg + (kt*64 + r)*64 + s*8, smemK + (i*256 + wv*64)*8);
            cp16(Vg + r*2048 + kt*64 + s*8, smemV + (i*256 + wv*64)*8);
        }
        __syncthreads();

        f32x4 sc[2][4];
#pragma unroll
        for (int mt = 0; mt < 2; ++mt)
#pragma unroll
            for (int nt = 0; nt < 4; ++nt) sc[mt][nt] = zf;
#pragma unroll
        for (int ks = 0; ks < 2; ++ks) {
            bf16x8 kf[4];
#pragma unroll
            for (int nt = 0; nt < 4; ++nt) {
                int row = nt*16 + l15;
                int sidx = (ks*4 + quad) ^ (row & 7);
                kf[nt] = *(const bf16x8*)(smemK + row*64 + sidx*8);
            }
#pragma unroll
            for (int mt = 0; mt < 2; ++mt)
#pragma unroll
                for (int nt = 0; nt < 4; ++nt)
                    sc[mt][nt] = __builtin_amdgcn_mfma_f32_16x16x32_bf16(qf[mt][ks], kf[nt], sc[mt][nt], 0, 0, 0);
        }

        // online softmax
#pragma unroll
        for (int mt = 0; mt < 2; ++mt) {
#pragma unroll
            for (int r = 0; r < 4; ++r) {
                int qrow = q0 + wv*32 + mt*16 + quad*4 + r;
                float mx = -1e30f;
#pragma unroll
                for (int nt = 0; nt < 4; ++nt) {
                    int key = kt*64 + nt*16 + l15;
                    float v = sc[mt][nt][r] * SC;
                    v = (key > qrow) ? -1e30f : v;
                    sc[mt][nt][r] = v;
                    mx = fmaxf(mx, v);
                }
#pragma unroll
                for (int d = 1; d < 16; d <<= 1) mx = fmaxf(mx, __shfl_xor(mx, d));
                float mnew = fmaxf(m_i[mt][r], mx);
                float alpha = exp2f((m_i[mt][r] - mnew) * LOG2E);
                m_i[mt][r] = mnew;
                float rs = 0.f;
#pragma unroll
                for (int nt = 0; nt < 4; ++nt) {
                    float p = exp2f((sc[mt][nt][r] - mnew) * LOG2E);
                    sc[mt][nt][r] = p;
                    rs += p;
                }
#pragma unroll
                for (int d = 1; d < 16; d <<= 1) rs += __shfl_xor(rs, d);
                l_i[mt][r] = l_i[mt][r] * alpha + rs;
#pragma unroll
                for (int dt = 0; dt < 4; ++dt) o[mt][dt][r] *= alpha;
                int prow = wv*32 + mt*16 + quad*4 + r;
#pragma unroll
                for (int nt = 0; nt < 4; ++nt)
                    smemP[prow*72 + nt*16 + l15] = f2bf(sc[mt][nt][r]);
            }
        }

        // PV: each wave reads only its own 32 P-rows (in-order DS within wave)
#pragma unroll
        for (int ks2 = 0; ks2 < 2; ++ks2) {
            bf16x8 pf[2], vf[4];
#pragma unroll
            for (int mt = 0; mt < 2; ++mt)
                pf[mt] = *(const bf16x8*)(smemP + (wv*32 + mt*16 + l15)*72 + ks2*32 + quad*8);
#pragma unroll
            for (int dt = 0; dt < 4; ++dt) {
                int row = dt*16 + l15;
                int sidx = (ks2*4 + quad) ^ (row & 7);
                vf[dt] = *(const bf16x8*)(smemV + row*64 + sidx*8);
            }
#pragma unroll
            for (int mt = 0; mt < 2; ++mt)
#pragma unroll
                for (int dt = 0; dt < 4; ++dt)
                    o[mt][dt] = __builtin_amdgcn_mfma_f32_16x16x32_bf16(pf[mt], vf[dt], o[mt][dt], 0, 0, 0);
        }
        __syncthreads();
    }

    // epilogue: normalize and write to attn [b*2048+s][h*64+d]
#pragma unroll
    for (int mt = 0; mt < 2; ++mt) {
#pragma unroll
        for (int r = 0; r < 4; ++r) {
            int qrow = q0 + wv*32 + mt*16 + quad*4 + r;
            float rl = 1.0f / l_i[mt][r];
#pragma unroll
            for (int dt = 0; dt < 4; ++dt)
                attn[(b*2048 + qrow)*1024 + h*64 + dt*16 + l15] = f2bf(o[mt][dt][r] * rl);
        }
    }
}

extern "C" void kernel_launch(void* const* d_in, const int* in_sizes, int n_in,
                              void* d_out, int out_size, void* d_ws, size_t ws_size,
                              hipStream_t stream) {
    const float* hidden = (const float*)d_in[0];
    // d_in[1] = causal_mask (reconstructed analytically, unused)
    const float* cosp = (const float*)d_in[2];
    const float* sinp = (const float*)d_in[3];
    const float* Wq = (const float*)d_in[4];
    const float* Wk = (const float*)d_in[5];
    const float* Wv = (const float*)d_in[6];
    const float* Wo = (const float*)d_in[7];
    const float* qw = (const float*)d_in[8];
    const float* kw = (const float*)d_in[9];
    float* out = (float*)d_out;

    char* ws = (char*)d_ws;
    u16* hA   = (u16*)(ws);                 // 16 MB  hidden bf16; reused as attn buffer later
    u16* WqT  = (u16*)(ws + 16777216);      // 2 MB
    u16* WkT  = (u16*)(ws + 18874368);      // 0.5 MB
    u16* WvT  = (u16*)(ws + 19398656);      // 0.5 MB
    u16* WoT  = (u16*)(ws + 19922944);      // 2 MB
    u16* Qws  = (u16*)(ws + 22020096);      // 16 MB
    u16* Kws  = (u16*)(ws + 38797312);      // 4 MB
    u16* Vws  = (u16*)(ws + 42991616);      // 4 MB
    u16* VTw  = (u16*)(ws + 47185920);      // 4 MB   -> total 51.4 MB
    u16* attn = hA;                         // alias: hA dead after QKV GEMM

    k_cvt_bf16<<<4096, 256, 0, stream>>>(hidden, hA);
    k_wtrans<<<dim3(16, 16), 256, 0, stream>>>(Wq, WqT, 1024, 1024);
    k_wtrans<<<dim3(4, 16), 256, 0, stream>>>(Wk, WkT, 1024, 256);
    k_wtrans<<<dim3(4, 16), 256, 0, stream>>>(Wv, WvT, 1024, 256);
    k_wtrans<<<dim3(16, 16), 256, 0, stream>>>(Wo, WoT, 1024, 1024);
    k_gemm<<<dim3(64, 12), 256, 0, stream>>>(hA, WqT, WkT, WvT, nullptr, Qws, Kws, Vws, 1);
    k_normrope<<<20480, 256, 0, stream>>>(Qws, Kws, qw, kw, cosp, sinp);
    k_vtrans<<<dim3(32, 16), 256, 0, stream>>>(Vws, VTw);
    k_attn<<<dim3(16, 16, 4), 256, 0, stream>>>(Qws, Kws, VTw, attn);
    k_gemm<<<dim3(64, 8), 256, 0, stream>>>(attn, WoT, nullptr, nullptr, out, nullptr, nullptr, nullptr, 0);
}

// Round 2
// 344.880 us; speedup vs baseline: 1.4365x; 1.4365x over previous
//
#include <hip/hip_runtime.h>

typedef unsigned short u16;
typedef unsigned int u32;

typedef __attribute__((ext_vector_type(8))) short bf16x8;
typedef __attribute__((ext_vector_type(4))) float f32x4;

#define SC 0.125f
#define QSCALE 0.18033688011112042f   // SC * log2(e)

__device__ __forceinline__ u16 f2bf(float x) {
    union { float f; u32 u; } v; v.f = x;
    u32 r = (v.u + 0x7FFFu + ((v.u >> 16) & 1u)) >> 16;
    return (u16)r;
}
__device__ __forceinline__ float bf2f(u16 x) {
    union { u32 u; float f; } v; v.u = ((u32)x) << 16;
    return v.f;
}
// pack two f32 -> two bf16 (round-half-up) in one v_perm
__device__ __forceinline__ u32 pk2(float x, float y) {
    u32 ax = __float_as_uint(x) + 0x8000u;
    u32 ay = __float_as_uint(y) + 0x8000u;
    return __builtin_amdgcn_perm(ay, ax, 0x07060302u);
}

__device__ __forceinline__ void cp16(const u16* g, u16* l) {
    __builtin_amdgcn_global_load_lds(
        (__attribute__((address_space(1))) void*)(g),
        (__attribute__((address_space(3))) void*)(l), 16, 0, 0);
}

// ---------------- hidden fp32 -> bf16 ----------------
__global__ void k_cvt_bf16(const float* __restrict__ src, u16* __restrict__ dst) {
    int i = (blockIdx.x * 256 + threadIdx.x) * 8;
    float4 a = *(const float4*)(src + i);
    float4 b = *(const float4*)(src + i + 4);
    ushort4 o0; o0.x = f2bf(a.x); o0.y = f2bf(a.y); o0.z = f2bf(a.z); o0.w = f2bf(a.w);
    ushort4 o1; o1.x = f2bf(b.x); o1.y = f2bf(b.y); o1.z = f2bf(b.z); o1.w = f2bf(b.w);
    *(ushort4*)(dst + i) = o0;
    *(ushort4*)(dst + i + 4) = o1;
}

// ---------------- W [K][N] fp32 -> Wt [N][K] bf16 ----------------
__global__ void k_wtrans(const float* __restrict__ W, u16* __restrict__ Wt, int K, int N) {
    __shared__ u16 t[64][72];
    int bx = blockIdx.x;            // n block
    int by = blockIdx.y;            // k block
    int r  = threadIdx.x >> 2;      // 0..63
    int cs = threadIdx.x & 3;       // 0..3
    const float* src = W + (by*64 + r)*N + bx*64 + cs*16;
#pragma unroll
    for (int j = 0; j < 16; j += 4) {
        float4 v = *(const float4*)(src + j);
        t[r][cs*16 + j + 0] = f2bf(v.x);
        t[r][cs*16 + j + 1] = f2bf(v.y);
        t[r][cs*16 + j + 2] = f2bf(v.z);
        t[r][cs*16 + j + 3] = f2bf(v.w);
    }
    __syncthreads();
    u16* dst = Wt + (bx*64 + r)*K + by*64 + cs*16;
#pragma unroll
    for (int j = 0; j < 16; ++j) dst[j] = t[cs*16 + j][r];
}

// ---------------- GEMM: C = A[8192][1024] * Bt^T, Bt is [N][1024] bf16 ----------------
__global__ __launch_bounds__(256) void k_gemm(
    const u16* __restrict__ A,
    const u16* __restrict__ Bq, const u16* __restrict__ Bk, const u16* __restrict__ Bv,
    float* __restrict__ outF,
    u16* __restrict__ outQ, u16* __restrict__ outK, u16* __restrict__ outV,
    int mode)
{
    __shared__ __align__(16) u16 At[128*32];
    __shared__ __align__(16) u16 Bt[128*32];
    int tid = threadIdx.x;
    int lane = tid & 63, wv = tid >> 6;
    int l15 = lane & 15, quad = lane >> 4;
    int wm = wv >> 1, wn = wv & 1;
    int mb = blockIdx.x, nb = blockIdx.y;

    const u16* Bsrc; int target; int colLocal0;
    if (mode == 0)      { Bsrc = Bq + nb*128*1024;      target = 3; colLocal0 = nb*128; }
    else if (nb < 8)    { Bsrc = Bq + nb*128*1024;      target = 0; colLocal0 = nb*128; }
    else if (nb < 10)   { Bsrc = Bk + (nb-8)*128*1024;  target = 1; colLocal0 = (nb-8)*128; }
    else                { Bsrc = Bv + (nb-10)*128*1024; target = 2; colLocal0 = (nb-10)*128; }
    const u16* Asrc = A + mb*128*1024;

    f32x4 zf = {0.f, 0.f, 0.f, 0.f};
    f32x4 acc[4][4];
#pragma unroll
    for (int i = 0; i < 4; ++i)
#pragma unroll
        for (int j = 0; j < 4; ++j) acc[i][j] = zf;

    for (int kt = 0; kt < 32; ++kt) {
#pragma unroll
        for (int i = 0; i < 2; ++i) {
            int q = i*256 + tid;
            int r = q >> 2, sidx = q & 3;
            int s = sidx ^ ((r >> 1) & 3);           // XOR swizzle of 16B segs
            cp16(Asrc + r*1024 + kt*32 + s*8, At + (i*256 + wv*64)*8);
            cp16(Bsrc + r*1024 + kt*32 + s*8, Bt + (i*256 + wv*64)*8);
        }
        __syncthreads();
        bf16x8 af[4], bfr[4];
#pragma unroll
        for (int mt = 0; mt < 4; ++mt) {
            int row = wm*64 + mt*16 + l15;
            int sidx = quad ^ ((row >> 1) & 3);
            af[mt] = *(const bf16x8*)(At + row*32 + sidx*8);
        }
#pragma unroll
        for (int nt = 0; nt < 4; ++nt) {
            int row = wn*64 + nt*16 + l15;
            int sidx = quad ^ ((row >> 1) & 3);
            bfr[nt] = *(const bf16x8*)(Bt + row*32 + sidx*8);
        }
#pragma unroll
        for (int mt = 0; mt < 4; ++mt)
#pragma unroll
            for (int nt = 0; nt < 4; ++nt)
                acc[mt][nt] = __builtin_amdgcn_mfma_f32_16x16x32_bf16(af[mt], bfr[nt], acc[mt][nt], 0, 0, 0);
        __syncthreads();
    }

#pragma unroll
    for (int mt = 0; mt < 4; ++mt) {
#pragma unroll
        for (int nt = 0; nt < 4; ++nt) {
#pragma unroll
            for (int rr = 0; rr < 4; ++rr) {
                int row = mb*128 + wm*64 + mt*16 + quad*4 + rr;
                int cl  = colLocal0 + wn*64 + nt*16 + l15;
                float v = acc[mt][nt][rr];
                if (target == 3) {
                    outF[row*1024 + cl] = v;
                } else {
                    int b = row >> 11, s = row & 2047;
                    int hh = cl >> 6, d = cl & 63;
                    u16 bv = f2bf(v);
                    if (target == 0)      outQ[((b*16 + hh)*2048 + s)*64 + d] = bv;
                    else if (target == 1) outK[((b*4  + hh)*2048 + s)*64 + d] = bv;
                    else                  outV[((b*4  + hh)*2048 + s)*64 + d] = bv;
                }
            }
        }
    }
}

// ---------------- RMSNorm + RoPE in place on Q (131072 rows) and K (32768 rows) ----------------
// Q additionally pre-scaled by SC*log2(e) so attention softmax runs in exp2 domain.
__global__ void k_normrope(u16* __restrict__ Q, u16* __restrict__ K,
                           const float* __restrict__ qw, const float* __restrict__ kw,
                           const float* __restrict__ cosp, const float* __restrict__ sinp)
{
    int row = blockIdx.x * 8 + (threadIdx.x >> 5);
    int t = threadIdx.x & 31;
    u16* base; const float* w; int s; float post;
    if (row < 131072) { base = Q + row*64; s = row & 2047; w = qw; post = QSCALE; }
    else { int r2 = row - 131072; base = K + r2*64; s = r2 & 2047; w = kw; post = 1.0f; }
    u32 packed = *(const u32*)(base + 2*t);
    float x0 = bf2f((u16)(packed & 0xffffu));
    float x1 = bf2f((u16)(packed >> 16));
    float ss = x0*x0 + x1*x1;
#pragma unroll
    for (int m = 1; m < 32; m <<= 1) ss += __shfl_xor(ss, m, 32);
    float inv = rsqrtf(ss * (1.0f/64.0f) + 1e-6f);
    float w0 = w[2*t], w1 = w[2*t+1];
    float c = cosp[s*64 + 2*t], sn = sinp[s*64 + 2*t];
    float xn0 = x0 * inv * w0, xn1 = x1 * inv * w1;
    float y0 = (xn0*c - xn1*sn) * post;
    float y1 = (xn1*c + xn0*sn) * post;
    *(u32*)(base + 2*t) = pk2(y0, y1);
}

// ---------------- V [bh][s][64] -> VT [bh][64][s] ----------------
__global__ void k_vtrans(const u16* __restrict__ V, u16* __restrict__ VT) {
    __shared__ u16 t[64][72];
    int sb = blockIdx.x;   // 0..31
    int bh = blockIdx.y;   // 0..15
    int r = threadIdx.x >> 2, cs = threadIdx.x & 3;
    const u16* src = V + (bh*2048 + sb*64 + r)*64 + cs*16;
    uint4 v0 = *(const uint4*)(src);
    uint4 v1 = *(const uint4*)(src + 8);
    *(uint4*)&t[r][cs*16]     = v0;
    *(uint4*)&t[r][cs*16 + 8] = v1;
    __syncthreads();
    u16* dst = VT + (bh*64 + r)*2048 + sb*64 + cs*16;
#pragma unroll
    for (int j = 0; j < 16; ++j) dst[j] = t[cs*16 + j][r];
}

// ---------------- flash attention, transposed-score formulation ----------------
// S^T = K·Q^T (keys on MFMA rows, q-rows on lanes) => key-reduction is in-register.
// O^T = V^T·P^T. Q pre-scaled by SC*log2e, so p = exp2(s - m).
__global__ __launch_bounds__(256, 4) void k_attn(
    const u16* __restrict__ Q, const u16* __restrict__ K,
    const u16* __restrict__ VT, u16* __restrict__ attn)
{
    __shared__ __align__(16) u16 smemP[128*72];   // P^T [qcol][64key + pad]; also Q stage / O transpose
    __shared__ __align__(16) u16 smemK[64*64];    // [key][d], seg-swizzled by row
    __shared__ __align__(16) u16 smemV[64*64];    // [d][key], seg-swizzled by row

    int tid = threadIdx.x;
    int lane = tid & 63, wv = tid >> 6;
    int l15 = lane & 15, quad = lane >> 4;
    int qt = 15 - blockIdx.x;                      // big causal blocks dispatch first
    int h = blockIdx.y, b = blockIdx.z;
    int q0 = qt * 128;
    const u16* Qg = Q + ((b*16 + h)*2048 + q0)*64;
    const u16* Kg = K + ((b*4 + (h >> 2))*2048)*64;
    const u16* Vg = VT + (b*4 + (h >> 2))*64*2048;

    // stage Q tile [128][64] (no swizzle; read once)
#pragma unroll
    for (int i = 0; i < 4; ++i) {
        int q = i*256 + tid;
        int r = q >> 3, s = q & 7;
        cp16(Qg + r*64 + s*8, smemP + (i*256 + wv*64)*8);
    }
    __syncthreads();
    // B-operand fragments of Q^T: lane n=l15 -> qrow (wave-local), k-group=quad
    bf16x8 qf[2][2];
#pragma unroll
    for (int nt = 0; nt < 2; ++nt)
#pragma unroll
        for (int ks = 0; ks < 2; ++ks)
            qf[nt][ks] = *(const bf16x8*)(smemP + (wv*32 + nt*16 + l15)*64 + ks*32 + quad*8);
    __syncthreads();   // P region may now be reused

    f32x4 zf = {0.f, 0.f, 0.f, 0.f};
    float m_i[2], l_i[2];
    f32x4 o[4][2];                                 // [d-tile][q-tile], O^T in C-layout
#pragma unroll
    for (int nt = 0; nt < 2; ++nt) { m_i[nt] = -1e30f; l_i[nt] = 0.f; }
#pragma unroll
    for (int mt = 0; mt < 4; ++mt)
#pragma unroll
        for (int nt = 0; nt < 2; ++nt) o[mt][nt] = zf;

    int qbase = q0 + wv*32;                        // wave's first q-row
    int ktmax = 2*qt + 1;
    for (int kt = 0; kt <= ktmax; ++kt) {
#pragma unroll
        for (int i = 0; i < 2; ++i) {
            int q = i*256 + tid;
            int r = q >> 3, sidx = q & 7;
            int s = sidx ^ (r & 7);
            cp16(Kg + (kt*64 + r)*64 + s*8, smemK + (i*256 + wv*64)*8);
            cp16(Vg + r*2048 + kt*64 + s*8, smemV + (i*256 + wv*64)*8);
        }
        __syncthreads();

        bool active = (kt*64 <= qbase + 31);       // wave-uniform
        if (active) {
            // ---- S^T = K·Q^T ----
            f32x4 sc[4][2];
#pragma unroll
            for (int mt = 0; mt < 4; ++mt)
#pragma unroll
                for (int nt = 0; nt < 2; ++nt) sc[mt][nt] = zf;
#pragma unroll
            for (int ks = 0; ks < 2; ++ks) {
                bf16x8 kf[4];
#pragma unroll
                for (int mt = 0; mt < 4; ++mt) {
                    int row = mt*16 + l15;
                    int sidx = (ks*4 + quad) ^ (row & 7);
                    kf[mt] = *(const bf16x8*)(smemK + row*64 + sidx*8);
                }
#pragma unroll
                for (int mt = 0; mt < 4; ++mt)
#pragma unroll
                    for (int nt = 0; nt < 2; ++nt)
                        sc[mt][nt] = __builtin_amdgcn_mfma_f32_16x16x32_bf16(kf[mt], qf[nt][ks], sc[mt][nt], 0, 0, 0);
            }

            bool needMask = (kt*64 + 63 > qbase);  // wave-uniform: diagonal band only
            int keyb = kt*64 + quad*4;
#pragma unroll
            for (int nt = 0; nt < 2; ++nt) {
                int qrow = qbase + nt*16 + l15;
                if (needMask) {
#pragma unroll
                    for (int mt = 0; mt < 4; ++mt)
#pragma unroll
                        for (int r = 0; r < 4; ++r)
                            if (keyb + mt*16 + r > qrow) sc[mt][nt][r] = -1e30f;
                }
                // in-register max over this lane's 16 keys, then cross-quad
                float mx = -1e30f;
#pragma unroll
                for (int mt = 0; mt < 4; ++mt)
#pragma unroll
                    for (int r = 0; r < 4; ++r) mx = fmaxf(mx, sc[mt][nt][r]);
                mx = fmaxf(mx, __shfl_xor(mx, 16));
                mx = fmaxf(mx, __shfl_xor(mx, 32));
                float mnew = fmaxf(m_i[nt], mx);
                float alpha = __builtin_amdgcn_exp2f(m_i[nt] - mnew);
                m_i[nt] = mnew;
                float rs = 0.f;
                int qcol = wv*32 + nt*16 + l15;
#pragma unroll
                for (int mt = 0; mt < 4; ++mt) {
                    float p0 = __builtin_amdgcn_exp2f(sc[mt][nt][0] - mnew);
                    float p1 = __builtin_amdgcn_exp2f(sc[mt][nt][1] - mnew);
                    float p2 = __builtin_amdgcn_exp2f(sc[mt][nt][2] - mnew);
                    float p3 = __builtin_amdgcn_exp2f(sc[mt][nt][3] - mnew);
                    rs += (p0 + p1) + (p2 + p3);
                    uint2 w; w.x = pk2(p0, p1); w.y = pk2(p2, p3);
                    *(uint2*)(smemP + qcol*72 + mt*16 + quad*4) = w;   // ds_write_b64
                }
                rs += __shfl_xor(rs, 16);
                rs += __shfl_xor(rs, 32);
                l_i[nt] = l_i[nt]*alpha + rs;
#pragma unroll
                for (int mt = 0; mt < 4; ++mt)
#pragma unroll
                    for (int r = 0; r < 4; ++r) o[mt][nt][r] *= alpha;  // alpha uniform per lane
            }

            // ---- O^T += V^T·P^T (wave reads only its own P columns; in-order DS) ----
#pragma unroll
            for (int ks2 = 0; ks2 < 2; ++ks2) {
                bf16x8 vf[4], pf[2];
#pragma unroll
                for (int nt = 0; nt < 2; ++nt)
                    pf[nt] = *(const bf16x8*)(smemP + (wv*32 + nt*16 + l15)*72 + ks2*32 + quad*8);
#pragma unroll
                for (int mt = 0; mt < 4; ++mt) {
                    int row = mt*16 + l15;
                    int sidx = (ks2*4 + quad) ^ (row & 7);
                    vf[mt] = *(const bf16x8*)(smemV + row*64 + sidx*8);
                }
#pragma unroll
                for (int mt = 0; mt < 4; ++mt)
#pragma unroll
                    for (int nt = 0; nt < 2; ++nt)
                        o[mt][nt] = __builtin_amdgcn_mfma_f32_16x16x32_bf16(vf[mt], pf[nt], o[mt][nt], 0, 0, 0);
            }
        }
        __syncthreads();
    }

    // epilogue: O^T -> LDS [qcol][d] -> coalesced global
#pragma unroll
    for (int nt = 0; nt < 2; ++nt) {
        float rl = 1.0f / l_i[nt];
        int qcol = wv*32 + nt*16 + l15;
#pragma unroll
        for (int mt = 0; mt < 4; ++mt) {
            uint2 w;
            w.x = pk2(o[mt][nt][0]*rl, o[mt][nt][1]*rl);
            w.y = pk2(o[mt][nt][2]*rl, o[mt][nt][3]*rl);
            *(uint2*)(smemP + qcol*72 + mt*16 + quad*4) = w;
        }
    }
    __syncthreads();
    {
        int r2 = tid >> 1, half = tid & 1;
        const u16* src = smemP + r2*72 + half*32;
        u16* dst = attn + (b*2048 + q0 + r2)*1024 + h*64 + half*32;
#pragma unroll
        for (int j = 0; j < 4; ++j)
            *(uint4*)(dst + j*8) = *(const uint4*)(src + j*8);
    }
}

extern "C" void kernel_launch(void* const* d_in, const int* in_sizes, int n_in,
                              void* d_out, int out_size, void* d_ws, size_t ws_size,
                              hipStream_t stream) {
    const float* hidden = (const float*)d_in[0];
    // d_in[1] = causal_mask (reconstructed analytically, unused)
    const float* cosp = (const float*)d_in[2];
    const float* sinp = (const float*)d_in[3];
    const float* Wq = (const float*)d_in[4];
    const float* Wk = (const float*)d_in[5];
    const float* Wv = (const float*)d_in[6];
    const float* Wo = (const float*)d_in[7];
    const float* qw = (const float*)d_in[8];
    const float* kw = (const float*)d_in[9];
    float* out = (float*)d_out;

    char* ws = (char*)d_ws;
    u16* hA   = (u16*)(ws);                 // 16 MB  hidden bf16; reused as attn buffer later
    u16* WqT  = (u16*)(ws + 16777216);      // 2 MB
    u16* WkT  = (u16*)(ws + 18874368);      // 0.5 MB
    u16* WvT  = (u16*)(ws + 19398656);      // 0.5 MB
    u16* WoT  = (u16*)(ws + 19922944);      // 2 MB
    u16* Qws  = (u16*)(ws + 22020096);      // 16 MB
    u16* Kws  = (u16*)(ws + 38797312);      // 4 MB
    u16* Vws  = (u16*)(ws + 42991616);      // 4 MB
    u16* VTw  = (u16*)(ws + 47185920);      // 4 MB   -> total 51.4 MB
    u16* attn = hA;                         // alias: hA dead after QKV GEMM

    k_cvt_bf16<<<4096, 256, 0, stream>>>(hidden, hA);
    k_wtrans<<<dim3(16, 16), 256, 0, stream>>>(Wq, WqT, 1024, 1024);
    k_wtrans<<<dim3(4, 16), 256, 0, stream>>>(Wk, WkT, 1024, 256);
    k_wtrans<<<dim3(4, 16), 256, 0, stream>>>(Wv, WvT, 1024, 256);
    k_wtrans<<<dim3(16, 16), 256, 0, stream>>>(Wo, WoT, 1024, 1024);
    k_gemm<<<dim3(64, 12), 256, 0, stream>>>(hA, WqT, WkT, WvT, nullptr, Qws, Kws, Vws, 1);
    k_normrope<<<20480, 256, 0, stream>>>(Qws, Kws, qw, kw, cosp, sinp);
    k_vtrans<<<dim3(32, 16), 256, 0, stream>>>(Vws, VTw);
    k_attn<<<dim3(16, 16, 4), 256, 0, stream>>>(Qws, Kws, VTw, attn);
    k_gemm<<<dim3(64, 8), 256, 0, stream>>>(attn, WoT, nullptr, nullptr, out, nullptr, nullptr, nullptr, 0);
}

// Round 3
// 332.716 us; speedup vs baseline: 1.4890x; 1.0366x over previous
//
#include <hip/hip_runtime.h>

typedef unsigned short u16;
typedef unsigned int u32;

typedef __attribute__((ext_vector_type(8))) short bf16x8;
typedef __attribute__((ext_vector_type(4))) float f32x4;

#define QSCALE 0.18033688011112042f   // (1/8) * log2(e)

__device__ __forceinline__ u16 f2bf(float x) {
    union { float f; u32 u; } v; v.f = x;
    u32 r = (v.u + 0x7FFFu + ((v.u >> 16) & 1u)) >> 16;
    return (u16)r;
}
__device__ __forceinline__ float bf2f(u16 x) {
    union { u32 u; float f; } v; v.u = ((u32)x) << 16;
    return v.f;
}
// pack two f32 -> two bf16 (round-half-up) in one v_perm
__device__ __forceinline__ u32 pk2(float x, float y) {
    u32 ax = __float_as_uint(x) + 0x8000u;
    u32 ay = __float_as_uint(y) + 0x8000u;
    return __builtin_amdgcn_perm(ay, ax, 0x07060302u);
}

__device__ __forceinline__ void cp16(const u16* g, u16* l) {
    __builtin_amdgcn_global_load_lds(
        (__attribute__((address_space(1))) void*)(g),
        (__attribute__((address_space(3))) void*)(l), 16, 0, 0);
}

// ---------------- fused prep: hidden fp32->bf16 + 4 weight transposes ----------------
// blocks [0,4096): cvt; [4096,4352): Wq; [4352,4416): Wk; [4416,4480): Wv; [4480,4736): Wo
__global__ void k_prep(const float* __restrict__ hidden, u16* __restrict__ hA,
                       const float* __restrict__ Wq, u16* __restrict__ WqT,
                       const float* __restrict__ Wk, u16* __restrict__ WkT,
                       const float* __restrict__ Wv, u16* __restrict__ WvT,
                       const float* __restrict__ Wo, u16* __restrict__ WoT) {
    __shared__ u16 t[64][72];
    int bid = blockIdx.x, tid = threadIdx.x;
    if (bid < 4096) {
        int i = (bid * 256 + tid) * 8;
        float4 a = *(const float4*)(hidden + i);
        float4 b = *(const float4*)(hidden + i + 4);
        ushort4 o0; o0.x = f2bf(a.x); o0.y = f2bf(a.y); o0.z = f2bf(a.z); o0.w = f2bf(a.w);
        ushort4 o1; o1.x = f2bf(b.x); o1.y = f2bf(b.y); o1.z = f2bf(b.z); o1.w = f2bf(b.w);
        *(ushort4*)(hA + i) = o0;
        *(ushort4*)(hA + i + 4) = o1;
        return;
    }
    int rb = bid - 4096;
    const float* W; u16* Wt; int N, bx, by;
    if (rb < 256)      { W = Wq; Wt = WqT; N = 1024; bx = rb & 15; by = rb >> 4; }
    else if (rb < 320) { W = Wk; Wt = WkT; N = 256;  rb -= 256; bx = rb & 3; by = rb >> 2; }
    else if (rb < 384) { W = Wv; Wt = WvT; N = 256;  rb -= 320; bx = rb & 3; by = rb >> 2; }
    else               { W = Wo; Wt = WoT; N = 1024; rb -= 384; bx = rb & 15; by = rb >> 4; }
    const int K = 1024;
    int rr = tid >> 2;      // 0..63
    int cs = tid & 3;       // 0..3
    const float* src = W + (by*64 + rr)*N + bx*64 + cs*16;
#pragma unroll
    for (int j = 0; j < 16; j += 4) {
        float4 v = *(const float4*)(src + j);
        t[rr][cs*16 + j + 0] = f2bf(v.x);
        t[rr][cs*16 + j + 1] = f2bf(v.y);
        t[rr][cs*16 + j + 2] = f2bf(v.z);
        t[rr][cs*16 + j + 3] = f2bf(v.w);
    }
    __syncthreads();
    u16* dst = Wt + (bx*64 + rr)*K + by*64 + cs*16;
#pragma unroll
    for (int j = 0; j < 16; ++j) dst[j] = t[cs*16 + j][rr];
}

// ---------------- GEMM staging helper ----------------
__device__ __forceinline__ void stage_ab(const u16* __restrict__ Asrc, const u16* __restrict__ Bsrc,
                                         int kt, u16* At, u16* Bt, int tid, int wv) {
#pragma unroll
    for (int i = 0; i < 2; ++i) {
        int q = i*256 + tid;
        int r = q >> 2, sidx = q & 3;
        int s = sidx ^ ((r >> 1) & 3);           // XOR swizzle of 16B segs
        cp16(Asrc + r*1024 + kt*32 + s*8, At + (i*256 + wv*64)*8);
        cp16(Bsrc + r*1024 + kt*32 + s*8, Bt + (i*256 + wv*64)*8);
    }
}

// ---------------- GEMM: C = A[8192][1024] * Bt^T, Bt is [N][1024] bf16 ----------------
// Double-buffered: stage kt+1 after the barrier publishing kt -> 1 barrier/iter, loads overlap MFMA.
__global__ __launch_bounds__(256) void k_gemm(
    const u16* __restrict__ A,
    const u16* __restrict__ Bq, const u16* __restrict__ Bk, const u16* __restrict__ Bv,
    float* __restrict__ outF,
    u16* __restrict__ outQ, u16* __restrict__ outK, u16* __restrict__ outV,
    int mode)
{
    __shared__ __align__(16) u16 At[2][128*32];
    __shared__ __align__(16) u16 Bt[2][128*32];
    int tid = threadIdx.x;
    int lane = tid & 63, wv = tid >> 6;
    int l15 = lane & 15, quad = lane >> 4;
    int wm = wv >> 1, wn = wv & 1;
    int mb = blockIdx.x, nb = blockIdx.y;

    const u16* Bsrc; int target; int colLocal0;
    if (mode == 0)      { Bsrc = Bq + nb*128*1024;      target = 3; colLocal0 = nb*128; }
    else if (nb < 8)    { Bsrc = Bq + nb*128*1024;      target = 0; colLocal0 = nb*128; }
    else if (nb < 10)   { Bsrc = Bk + (nb-8)*128*1024;  target = 1; colLocal0 = (nb-8)*128; }
    else                { Bsrc = Bv + (nb-10)*128*1024; target = 2; colLocal0 = (nb-10)*128; }
    const u16* Asrc = A + mb*128*1024;

    f32x4 zf = {0.f, 0.f, 0.f, 0.f};
    f32x4 acc[4][4];
#pragma unroll
    for (int i = 0; i < 4; ++i)
#pragma unroll
        for (int j = 0; j < 4; ++j) acc[i][j] = zf;

    stage_ab(Asrc, Bsrc, 0, At[0], Bt[0], tid, wv);
    __syncthreads();

    for (int kt = 0; kt < 32; ++kt) {
        int cur = kt & 1;
        if (kt < 31) stage_ab(Asrc, Bsrc, kt + 1, At[cur ^ 1], Bt[cur ^ 1], tid, wv);
        bf16x8 af[4], bfr[4];
#pragma unroll
        for (int mt = 0; mt < 4; ++mt) {
            int row = wm*64 + mt*16 + l15;
            int sidx = quad ^ ((row >> 1) & 3);
            af[mt] = *(const bf16x8*)(At[cur] + row*32 + sidx*8);
        }
#pragma unroll
        for (int nt = 0; nt < 4; ++nt) {
            int row = wn*64 + nt*16 + l15;
            int sidx = quad ^ ((row >> 1) & 3);
            bfr[nt] = *(const bf16x8*)(Bt[cur] + row*32 + sidx*8);
        }
#pragma unroll
        for (int mt = 0; mt < 4; ++mt)
#pragma unroll
            for (int nt = 0; nt < 4; ++nt)
                acc[mt][nt] = __builtin_amdgcn_mfma_f32_16x16x32_bf16(af[mt], bfr[nt], acc[mt][nt], 0, 0, 0);
        __syncthreads();
    }

#pragma unroll
    for (int mt = 0; mt < 4; ++mt) {
#pragma unroll
        for (int nt = 0; nt < 4; ++nt) {
#pragma unroll
            for (int rr = 0; rr < 4; ++rr) {
                int row = mb*128 + wm*64 + mt*16 + quad*4 + rr;
                int cl  = colLocal0 + wn*64 + nt*16 + l15;
                float v = acc[mt][nt][rr];
                if (target == 3) {
                    outF[row*1024 + cl] = v;
                } else {
                    int b = row >> 11, s = row & 2047;
                    int hh = cl >> 6, d = cl & 63;
                    u16 bv = f2bf(v);
                    if (target == 0)      outQ[((b*16 + hh)*2048 + s)*64 + d] = bv;
                    else if (target == 1) outK[((b*4  + hh)*2048 + s)*64 + d] = bv;
                    else                  outV[((b*4  + hh)*2048 + s)*64 + d] = bv;
                }
            }
        }
    }
}

// ---------------- fused RMSNorm+RoPE (Q,K) + V transpose ----------------
// blocks [0,20480): normrope (8 rows each); [20480,20992): vtrans
__global__ void k_nv(u16* __restrict__ Q, u16* __restrict__ K,
                     const float* __restrict__ qw, const float* __restrict__ kw,
                     const float* __restrict__ cosp, const float* __restrict__ sinp,
                     const u16* __restrict__ V, u16* __restrict__ VT)
{
    __shared__ u16 t[64][72];
    int bid = blockIdx.x, tid = threadIdx.x;
    if (bid < 20480) {
        int row = bid * 8 + (tid >> 5);
        int tl = tid & 31;
        u16* base; const float* w; int s; float post;
        if (row < 131072) { base = Q + row*64; s = row & 2047; w = qw; post = QSCALE; }
        else { int r2 = row - 131072; base = K + r2*64; s = r2 & 2047; w = kw; post = 1.0f; }
        u32 packed = *(const u32*)(base + 2*tl);
        float x0 = bf2f((u16)(packed & 0xffffu));
        float x1 = bf2f((u16)(packed >> 16));
        float ss = x0*x0 + x1*x1;
#pragma unroll
        for (int m = 1; m < 32; m <<= 1) ss += __shfl_xor(ss, m, 32);
        float inv = rsqrtf(ss * (1.0f/64.0f) + 1e-6f);
        float w0 = w[2*tl], w1 = w[2*tl+1];
        float c = cosp[s*64 + 2*tl], sn = sinp[s*64 + 2*tl];
        float xn0 = x0 * inv * w0, xn1 = x1 * inv * w1;
        float y0 = (xn0*c - xn1*sn) * post;
        float y1 = (xn1*c + xn0*sn) * post;
        *(u32*)(base + 2*tl) = pk2(y0, y1);
        return;
    }
    int idx = bid - 20480;
    int sb = idx & 31, bh = idx >> 5;
    int r = tid >> 2, cs = tid & 3;
    const u16* src = V + (bh*2048 + sb*64 + r)*64 + cs*16;
    uint4 v0 = *(const uint4*)(src);
    uint4 v1 = *(const uint4*)(src + 8);
    *(uint4*)&t[r][cs*16]     = v0;
    *(uint4*)&t[r][cs*16 + 8] = v1;
    __syncthreads();
    u16* dst = VT + (bh*64 + r)*2048 + sb*64 + cs*16;
#pragma unroll
    for (int j = 0; j < 16; ++j) dst[j] = t[cs*16 + j][r];
}

// ---------------- attention staging helper ----------------
__device__ __forceinline__ void stage_kv(const u16* __restrict__ Kg, const u16* __restrict__ Vg,
                                         int kt, u16* sK, u16* sV, int tid, int wv) {
#pragma unroll
    for (int i = 0; i < 2; ++i) {
        int q = i*256 + tid;
        int r = q >> 3, sidx = q & 7;
        int s = sidx ^ (r & 7);
        cp16(Kg + (kt*64 + r)*64 + s*8, sK + (i*256 + wv*64)*8);
        cp16(Vg + r*2048 + kt*64 + s*8, sV + (i*256 + wv*64)*8);
    }
}

// ---------------- flash attention, transposed-score + pipelined KV ----------------
// S^T = K·Q^T; O^T = V^T·P^T. Q pre-scaled by SC*log2e -> p = exp2(s - m).
// Double-buffered K/V: stage kt+1 after barrier publishing kt -> 1 barrier/tile.
// P region XOR-swizzled on 16B granules (g ^= row&7): conflict-even b64 writes / b128 reads.
__global__ __launch_bounds__(256, 4) void k_attn(
    const u16* __restrict__ Q, const u16* __restrict__ K,
    const u16* __restrict__ VT, u16* __restrict__ attn)
{
    __shared__ __align__(16) u16 smemP[128*64];     // P^T swizzled; also Q stage / O transpose
    __shared__ __align__(16) u16 smemK[2][64*64];   // [key][d], seg-swizzled by row
    __shared__ __align__(16) u16 smemV[2][64*64];   // [d][key], seg-swizzled by row

    int tid = threadIdx.x;
    int lane = tid & 63, wv = tid >> 6;
    int l15 = lane & 15, quad = lane >> 4;
    int qt = 15 - blockIdx.x;                      // big causal blocks dispatch first
    int h = blockIdx.y, b = blockIdx.z;
    int q0 = qt * 128;
    const u16* Qg = Q + ((b*16 + h)*2048 + q0)*64;
    const u16* Kg = K + ((b*4 + (h >> 2))*2048)*64;
    const u16* Vg = VT + (b*4 + (h >> 2))*64*2048;

    // stage KV tile 0 (overlaps Q setup), then Q tile [128][64]
    stage_kv(Kg, Vg, 0, smemK[0], smemV[0], tid, wv);
#pragma unroll
    for (int i = 0; i < 4; ++i) {
        int q = i*256 + tid;
        int r = q >> 3, s = q & 7;
        cp16(Qg + r*64 + s*8, smemP + (i*256 + wv*64)*8);
    }
    __syncthreads();
    bf16x8 qf[2][2];
#pragma unroll
    for (int nt = 0; nt < 2; ++nt)
#pragma unroll
        for (int ks = 0; ks < 2; ++ks)
            qf[nt][ks] = *(const bf16x8*)(smemP + (wv*32 + nt*16 + l15)*64 + ks*32 + quad*8);
    __syncthreads();   // P region may now be reused

    f32x4 zf = {0.f, 0.f, 0.f, 0.f};
    float m_i[2], l_i[2];
    f32x4 o[4][2];                                 // [d-tile][q-tile], O^T in C-layout
#pragma unroll
    for (int nt = 0; nt < 2; ++nt) { m_i[nt] = -1e30f; l_i[nt] = 0.f; }
#pragma unroll
    for (int mt = 0; mt < 4; ++mt)
#pragma unroll
        for (int nt = 0; nt < 2; ++nt) o[mt][nt] = zf;

    int qbase = q0 + wv*32;                        // wave's first q-row
    int ktmax = 2*qt + 1;
    for (int kt = 0; kt <= ktmax; ++kt) {
        int cur = kt & 1;
        if (kt < ktmax) stage_kv(Kg, Vg, kt + 1, smemK[cur ^ 1], smemV[cur ^ 1], tid, wv);

        bool active = (kt*64 <= qbase + 31);       // wave-uniform
        if (active) {
            // ---- S^T = K·Q^T ----
            f32x4 sc[4][2];
#pragma unroll
            for (int mt = 0; mt < 4; ++mt)
#pragma unroll
                for (int nt = 0; nt < 2; ++nt) sc[mt][nt] = zf;
#pragma unroll
            for (int ks = 0; ks < 2; ++ks) {
                bf16x8 kf[4];
#pragma unroll
                for (int mt = 0; mt < 4; ++mt) {
                    int row = mt*16 + l15;
                    int sidx = (ks*4 + quad) ^ (row & 7);
                    kf[mt] = *(const bf16x8*)(smemK[cur] + row*64 + sidx*8);
                }
#pragma unroll
                for (int mt = 0; mt < 4; ++mt)
#pragma unroll
                    for (int nt = 0; nt < 2; ++nt)
                        sc[mt][nt] = __builtin_amdgcn_mfma_f32_16x16x32_bf16(kf[mt], qf[nt][ks], sc[mt][nt], 0, 0, 0);
            }

            bool needMask = (kt*64 + 63 > qbase);  // wave-uniform: diagonal band only
            int keyb = kt*64 + quad*4;
#pragma unroll
            for (int nt = 0; nt < 2; ++nt) {
                int qrow = qbase + nt*16 + l15;
                if (needMask) {
#pragma unroll
                    for (int mt = 0; mt < 4; ++mt)
#pragma unroll
                        for (int r = 0; r < 4; ++r)
                            if (keyb + mt*16 + r > qrow) sc[mt][nt][r] = -1e30f;
                }
                float mx = -1e30f;
#pragma unroll
                for (int mt = 0; mt < 4; ++mt)
#pragma unroll
                    for (int r = 0; r < 4; ++r) mx = fmaxf(mx, sc[mt][nt][r]);
                mx = fmaxf(mx, __shfl_xor(mx, 16));
                mx = fmaxf(mx, __shfl_xor(mx, 32));
                float mnew = fmaxf(m_i[nt], mx);
                float alpha = __builtin_amdgcn_exp2f(m_i[nt] - mnew);
                m_i[nt] = mnew;
                float rs = 0.f;
                int qcol = wv*32 + nt*16 + l15;
#pragma unroll
                for (int mt = 0; mt < 4; ++mt) {
                    float p0 = __builtin_amdgcn_exp2f(sc[mt][nt][0] - mnew);
                    float p1 = __builtin_amdgcn_exp2f(sc[mt][nt][1] - mnew);
                    float p2 = __builtin_amdgcn_exp2f(sc[mt][nt][2] - mnew);
                    float p3 = __builtin_amdgcn_exp2f(sc[mt][nt][3] - mnew);
                    rs += (p0 + p1) + (p2 + p3);
                    uint2 w; w.x = pk2(p0, p1); w.y = pk2(p2, p3);
                    int gw = (mt*2 + (quad >> 1)) ^ (qcol & 7);
                    *(uint2*)(smemP + qcol*64 + gw*8 + (quad & 1)*4) = w;   // ds_write_b64, bank-even
                }
                rs += __shfl_xor(rs, 16);
                rs += __shfl_xor(rs, 32);
                l_i[nt] = l_i[nt]*alpha + rs;
#pragma unroll
                for (int mt = 0; mt < 4; ++mt)
#pragma unroll
                    for (int r = 0; r < 4; ++r) o[mt][nt][r] *= alpha;
            }

            // ---- O^T += V^T·P^T (wave-private P columns; no barrier needed) ----
#pragma unroll
            for (int ks2 = 0; ks2 < 2; ++ks2) {
                bf16x8 vf[4], pf[2];
#pragma unroll
                for (int nt = 0; nt < 2; ++nt) {
                    int qcol = wv*32 + nt*16 + l15;
                    int gr = (ks2*4 + quad) ^ (qcol & 7);
                    pf[nt] = *(const bf16x8*)(smemP + qcol*64 + gr*8);
                }
#pragma unroll
                for (int mt = 0; mt < 4; ++mt) {
                    int row = mt*16 + l15;
                    int sidx = (ks2*4 + quad) ^ (row & 7);
                    vf[mt] = *(const bf16x8*)(smemV[cur] + row*64 + sidx*8);
                }
#pragma unroll
                for (int mt = 0; mt < 4; ++mt)
#pragma unroll
                    for (int nt = 0; nt < 2; ++nt)
                        o[mt][nt] = __builtin_amdgcn_mfma_f32_16x16x32_bf16(vf[mt], pf[nt], o[mt][nt], 0, 0, 0);
            }
        }
        __syncthreads();   // publishes buf[cur^1]; drains overlapped loads
    }

    // epilogue: O^T -> LDS (swizzled) -> coalesced global
#pragma unroll
    for (int nt = 0; nt < 2; ++nt) {
        float rl = 1.0f / l_i[nt];
        int qcol = wv*32 + nt*16 + l15;
#pragma unroll
        for (int mt = 0; mt < 4; ++mt) {
            uint2 w;
            w.x = pk2(o[mt][nt][0]*rl, o[mt][nt][1]*rl);
            w.y = pk2(o[mt][nt][2]*rl, o[mt][nt][3]*rl);
            int gw = (mt*2 + (quad >> 1)) ^ (qcol & 7);
            *(uint2*)(smemP + qcol*64 + gw*8 + (quad & 1)*4) = w;
        }
    }
    __syncthreads();
    {
        int r2 = tid >> 1, half = tid & 1;
        u16* dst = attn + (b*2048 + q0 + r2)*1024 + h*64 + half*32;
#pragma unroll
        for (int j = 0; j < 4; ++j) {
            int gr = (half*4 + j) ^ (r2 & 7);
            *(uint4*)(dst + j*8) = *(const uint4*)(smemP + r2*64 + gr*8);
        }
    }
}

extern "C" void kernel_launch(void* const* d_in, const int* in_sizes, int n_in,
                              void* d_out, int out_size, void* d_ws, size_t ws_size,
                              hipStream_t stream) {
    const float* hidden = (const float*)d_in[0];
    // d_in[1] = causal_mask (reconstructed analytically, unused)
    const float* cosp = (const float*)d_in[2];
    const float* sinp = (const float*)d_in[3];
    const float* Wq = (const float*)d_in[4];
    const float* Wk = (const float*)d_in[5];
    const float* Wv = (const float*)d_in[6];
    const float* Wo = (const float*)d_in[7];
    const float* qw = (const float*)d_in[8];
    const float* kw = (const float*)d_in[9];
    float* out = (float*)d_out;

    char* ws = (char*)d_ws;
    u16* hA   = (u16*)(ws);                 // 16 MB  hidden bf16; reused as attn buffer later
    u16* WqT  = (u16*)(ws + 16777216);      // 2 MB
    u16* WkT  = (u16*)(ws + 18874368);      // 0.5 MB
    u16* WvT  = (u16*)(ws + 19398656);      // 0.5 MB
    u16* WoT  = (u16*)(ws + 19922944);      // 2 MB
    u16* Qws  = (u16*)(ws + 22020096);      // 16 MB
    u16* Kws  = (u16*)(ws + 38797312);      // 4 MB
    u16* Vws  = (u16*)(ws + 42991616);      // 4 MB
    u16* VTw  = (u16*)(ws + 47185920);      // 4 MB   -> total 51.4 MB
    u16* attn = hA;                         // alias: hA dead after QKV GEMM

    k_prep<<<4736, 256, 0, stream>>>(hidden, hA, Wq, WqT, Wk, WkT, Wv, WvT, Wo, WoT);
    k_gemm<<<dim3(64, 12), 256, 0, stream>>>(hA, WqT, WkT, WvT, nullptr, Qws, Kws, Vws, 1);
    k_nv<<<20992, 256, 0, stream>>>(Qws, Kws, qw, kw, cosp, sinp, Vws, VTw);
    k_attn<<<dim3(16, 16, 4), 256, 0, stream>>>(Qws, Kws, VTw, attn);
    k_gemm<<<dim3(64, 8), 256, 0, stream>>>(attn, WoT, nullptr, nullptr, out, nullptr, nullptr, nullptr, 0);
}